// Round 5
// baseline (336.048 us; speedup 1.0000x reference)
//
#include <hip/hip_runtime.h>
#include <hip/hip_bf16.h>

// Problem constants (Qwen3-Next linear attention defaults)
#define S_LEN   256
#define HID     2048
#define NVH     32
#define KEYDIM  512
#define VALDIM  4096
#define CONVDIM 5120
#define QKVZ_N  9216
#define EPS_F   1e-6f

typedef __attribute__((ext_vector_type(8))) short bf16x8;
typedef __attribute__((ext_vector_type(4))) float f32x4;

__device__ __forceinline__ unsigned short f2bf(float f) {
    union { float f; unsigned int i; } v; v.f = f;
    unsigned int x = v.i;
    return (unsigned short)((x + 0x7FFFu + ((x >> 16) & 1u)) >> 16); // RNE
}
__device__ __forceinline__ unsigned int pk2(float x, float y) {
    union { __hip_bfloat162 h; unsigned int u; } c;
    c.h = __float22bfloat162_rn(float2{x, y});
    return c.u;
}
__device__ __forceinline__ float4 asf4(uint4 u) {
    union { uint4 u; float4 f; } c; c.u = u; return c.f;
}
__device__ __forceinline__ uint4 cvt8_pack(float4 a, float4 b) {
    uint4 r;
    r.x = pk2(a.x, a.y); r.y = pk2(a.z, a.w);
    r.z = pk2(b.x, b.y); r.w = pk2(b.z, b.w);
    return r;
}
__device__ __forceinline__ float sigmoidf(float x) { return 1.f / (1.f + __expf(-x)); }

// ---------------------------------------------------------------------------
// Split-K MFMA GEMM, tile 256(M-full) x 64(N), BK=64.
// A bf16 [256,K]; B fp32 [N,K] (cvt->bf16 in staging; read exactly ONCE
// across the grid since M-tile = full M). 4 waves, wave w owns m-rows
// w*64..w*64+63; all waves share the 64-wide B tile.
// mfma_f32_16x16x32_bf16: A-frag A[m=l16][k=quad*8+j]; C/D row=quad*4+r, col=l16.
// ---------------------------------------------------------------------------
__global__ __launch_bounds__(256, 3)
void gemm_tile(const unsigned short* __restrict__ A, const float* __restrict__ B,
               float* __restrict__ Cpart, int N, int K, int kc) {
    __shared__ __align__(16) unsigned short As[256][72]; // 144B row stride
    __shared__ __align__(16) unsigned short Bs[64][72];

    const int tid  = threadIdx.x;
    const int lane = tid & 63, wave = tid >> 6;
    const int quad = lane >> 4, l16 = lane & 15;
    const int n0   = blockIdx.x * 64;
    const int kbeg = blockIdx.z * kc;
    const int niter = kc >> 6;           // BK = 64

    const int ar = tid >> 2;             // 0..63 (+64p)
    const int ac = (tid & 3) << 4;       // element col 0,16,32,48

    f32x4 acc[4][4];
#pragma unroll
    for (int i = 0; i < 4; i++)
#pragma unroll
        for (int j = 0; j < 4; j++) acc[i][j] = (f32x4){0.f, 0.f, 0.f, 0.f};

    uint4 qa[8], qb[4];
    auto ld_tiles = [&](int kk) {
#pragma unroll
        for (int p = 0; p < 4; p++) {
            const unsigned short* a = A + (size_t)(ar + 64 * p) * K + kk + ac;
            qa[2 * p]     = *(const uint4*)a;
            qa[2 * p + 1] = *(const uint4*)(a + 8);
        }
        const float* b = B + (size_t)(n0 + ar) * K + kk + ac;
#pragma unroll
        for (int i = 0; i < 4; i++) qb[i] = *(const uint4*)(b + 4 * i);
    };
    auto st_tiles = [&]() {
#pragma unroll
        for (int p = 0; p < 4; p++) {
            *(uint4*)(&As[ar + 64 * p][ac])     = qa[2 * p];
            *(uint4*)(&As[ar + 64 * p][ac + 8]) = qa[2 * p + 1];
        }
        *(uint4*)(&Bs[ar][ac])     = cvt8_pack(asf4(qb[0]), asf4(qb[1]));
        *(uint4*)(&Bs[ar][ac + 8]) = cvt8_pack(asf4(qb[2]), asf4(qb[3]));
    };

    ld_tiles(kbeg);
    st_tiles();
    __syncthreads();

    for (int it = 0; it < niter; ++it) {
        if (it + 1 < niter) ld_tiles(kbeg + (it + 1) * 64);

        bf16x8 af[2][4], bfr[2][4];
#pragma unroll
        for (int t = 0; t < 4; t++) {
#pragma unroll
            for (int ks = 0; ks < 2; ks++) {
                af[ks][t]  = *(const bf16x8*)(&As[wave * 64 + t * 16 + l16][ks * 32 + quad * 8]);
                bfr[ks][t] = *(const bf16x8*)(&Bs[t * 16 + l16][ks * 32 + quad * 8]);
            }
        }
#pragma unroll
        for (int ks = 0; ks < 2; ks++)
#pragma unroll
            for (int i = 0; i < 4; i++)
#pragma unroll
                for (int j = 0; j < 4; j++)
                    acc[i][j] = __builtin_amdgcn_mfma_f32_16x16x32_bf16(af[ks][i], bfr[ks][j], acc[i][j], 0, 0, 0);

        if (it + 1 < niter) {
            __syncthreads();
            st_tiles();
            __syncthreads();
        }
    }

    float* C = Cpart + (size_t)blockIdx.z * 256 * N;
#pragma unroll
    for (int i = 0; i < 4; i++)
#pragma unroll
        for (int j = 0; j < 4; j++)
#pragma unroll
            for (int r = 0; r < 4; r++) {
                int row = wave * 64 + i * 16 + quad * 4 + r;
                int col = n0 + j * 16 + l16;
                C[(size_t)row * N + col] = acc[i][j][r];
            }
}

// sum P split-K partials, float4-vectorized
template<int P>
__global__ void reduce_sum(const float* __restrict__ part, float* __restrict__ out, int n) {
    int i = (blockIdx.x * 256 + threadIdx.x) * 4;
    if (i >= n) return;
    float4 s = *(const float4*)(part + i);
#pragma unroll
    for (int p = 1; p < P; p++) {
        float4 v = *(const float4*)(part + (size_t)p * n + i);
        s.x += v.x; s.y += v.y; s.z += v.z; s.w += v.w;
    }
    *(float4*)(out + i) = s;
}

// ba = hidden @ w_ba^T  [256,64]  +  hs -> bf16 copy (A operand for GEMM1).
__global__ __launch_bounds__(256)
void ba_proj(const float* __restrict__ hs,
             const float* __restrict__ w_ba,
             float* __restrict__ ba,
             unsigned short* __restrict__ hs_bf) {
    int s = blockIdx.x;
    int n = threadIdx.x & 63, seg = threadIdx.x >> 6;
    const float* x = hs + (size_t)s * HID + seg * 512;
    const float* w = w_ba + (size_t)n * HID + seg * 512;
    float acc = 0.f;
#pragma unroll 4
    for (int k = 0; k < 512; k += 4) {
        float4 xv = *(const float4*)(x + k);
        float4 wv = *(const float4*)(w + k);
        acc += xv.x * wv.x + xv.y * wv.y + xv.z * wv.z + xv.w * wv.w;
    }
    __shared__ float parts[4][64];
    parts[seg][n] = acc;
    // bf16 copy of this row: thread covers cols tid*8..tid*8+7
    int c = threadIdx.x * 8;
    float4 h0 = *(const float4*)(hs + (size_t)s * HID + c);
    float4 h1 = *(const float4*)(hs + (size_t)s * HID + c + 4);
    *(uint4*)(hs_bf + (size_t)s * HID + c) = cvt8_pack(h0, h1);
    __syncthreads();
    if (threadIdx.x < 64)
        ba[s * 64 + threadIdx.x] = parts[0][threadIdx.x] + parts[1][threadIdx.x]
                                 + parts[2][threadIdx.x] + parts[3][threadIdx.x];
}

// fused: sum 4 qkvz partials + causal depthwise conv (K=4) + silu, for qkv cols
__global__ void conv_red4(const float* __restrict__ part,
                          const float* __restrict__ conv_w,
                          float* __restrict__ out) {
    int idx = blockIdx.x * blockDim.x + threadIdx.x;
    int s = idx / CONVDIM, c = idx % CONVDIM;
    const size_t PSTR = (size_t)S_LEN * QKVZ_N;
    float acc = 0.f;
#pragma unroll
    for (int j = 0; j < 4; j++) {
        int t = s - 3 + j;
        if (t >= 0) {
            const float* p = part + (size_t)t * QKVZ_N + c;
            float q = p[0] + p[PSTR] + p[2 * PSTR] + p[3 * PSTR];
            acc += q * conv_w[c * 4 + j];
        }
    }
    out[idx] = acc * sigmoidf(acc); // silu
}

// fused flash-style: scores (QK^T * scale * beta_g, causal) -> @V -> gated
// RMSNorm -> bf16 normed.  Block = (s-tile of 16, v-head n).  z read from the
// un-reduced qkvz partials (cols 5120..9215).
__global__ __launch_bounds__(256)
void attn_fused(const float* __restrict__ conv, const float* __restrict__ ba,
                const float* __restrict__ dt_bias, const float* __restrict__ part,
                const float* __restrict__ norm_w,
                unsigned short* __restrict__ normed) {
    const int st = blockIdx.x, n = blockIdx.y, hk = n >> 3;
    const int s0 = st * 16;
    __shared__ float Qs[16][132], Ks[16][132], Vs[16][132], Ss[16][17];
    const int tid = threadIdx.x, sy = tid >> 4, dx = tid & 15;

    {   // stage Q tile
        const float* qp = conv + (size_t)(s0 + sy) * CONVDIM + hk * 128 + dx * 8;
        *(float4*)&Qs[sy][dx * 8]     = *(const float4*)qp;
        *(float4*)&Qs[sy][dx * 8 + 4] = *(const float4*)(qp + 4);
    }
    float acc[8] = {0.f, 0.f, 0.f, 0.f, 0.f, 0.f, 0.f, 0.f};
    const float dtb = dt_bias[n];

    for (int t0 = 0; t0 <= s0; t0 += 16) {
        const float* kp = conv + (size_t)(t0 + sy) * CONVDIM + KEYDIM + hk * 128 + dx * 8;
        const float* vp = conv + (size_t)(t0 + sy) * CONVDIM + 2 * KEYDIM + n * 128 + dx * 8;
        *(float4*)&Ks[sy][dx * 8]     = *(const float4*)kp;
        *(float4*)&Ks[sy][dx * 8 + 4] = *(const float4*)(kp + 4);
        *(float4*)&Vs[sy][dx * 8]     = *(const float4*)vp;
        *(float4*)&Vs[sy][dx * 8 + 4] = *(const float4*)(vp + 4);
        __syncthreads();
        // scores tile: thread (sy, dx) -> S[s0+sy][t0+dx]
        float dot = 0.f;
#pragma unroll 8
        for (int d = 0; d < 128; d += 4) {
            float4 q = *(const float4*)&Qs[sy][d];
            float4 k = *(const float4*)&Ks[dx][d];
            dot += q.x * k.x + q.y * k.y + q.z * k.z + q.w * k.w;
        }
        int t = t0 + dx, s = s0 + sy;
        float bg = sigmoidf(ba[t * 64 + n] + dtb);
        Ss[sy][dx] = (t <= s) ? dot * 0.08838834764831845f * bg : 0.f;
        __syncthreads();
#pragma unroll
        for (int j = 0; j < 16; j++) {
            float sv = Ss[sy][j];
#pragma unroll
            for (int r = 0; r < 8; r++) acc[r] += sv * Vs[j][dx + 16 * r];
        }
        __syncthreads();
    }
    // gated RMSNorm over the 128-wide row (16 lanes x 8 regs)
    float ss = 0.f;
#pragma unroll
    for (int r = 0; r < 8; r++) ss += acc[r] * acc[r];
#pragma unroll
    for (int m = 1; m < 16; m <<= 1) ss += __shfl_xor(ss, m, 64);
    float inv = rsqrtf(ss * (1.f / 128.f) + EPS_F);
    const size_t PSTR = (size_t)S_LEN * QKVZ_N;
    const float* zb = part + (size_t)(s0 + sy) * QKVZ_N + CONVDIM + n * 128;
    unsigned short* op = normed + ((size_t)(s0 + sy) * NVH + n) * 128;
#pragma unroll
    for (int r = 0; r < 8; r++) {
        int d = dx + 16 * r;
        float z = zb[d] + zb[d + PSTR] + zb[d + 2 * PSTR] + zb[d + 3 * PSTR];
        float val = acc[r] * inv * norm_w[d] * (z * sigmoidf(z));
        op[d] = f2bf(val);
    }
}

extern "C" void kernel_launch(void* const* d_in, const int* in_sizes, int n_in,
                              void* d_out, int out_size, void* d_ws, size_t ws_size,
                              hipStream_t stream) {
    const float* hs      = (const float*)d_in[0];
    const float* w_qkvz  = (const float*)d_in[1];
    const float* w_ba    = (const float*)d_in[2];
    const float* w_out   = (const float*)d_in[3];
    const float* conv_w  = (const float*)d_in[4];
    const float* dt_bias = (const float*)d_in[5];
    const float* norm_w  = (const float*)d_in[7];

    // Workspace overlay (ws_size >= 54 MiB, proven in R4 by WRITE_SIZE=4x9.44MB).
    char* ws = (char*)d_ws;
    float* scratch1        = (float*)ws;                    // 4 x 9.44 MB  [gemm1 .. attn_fused]
    float* conv            = (float*)(ws + 37748736);       // 5.24 MB      [conv_red4 .. attn_fused]
    float* ba              = (float*)(ws + 42991616);       // 64 KB
    unsigned short* normed = (unsigned short*)(ws + 43057152); // 2.10 MB   [attn_fused .. gemm2]
    unsigned short* hs_bf  = (unsigned short*)(ws + 45154304); // 1.05 MB   [ba_proj .. gemm1]
    float* scratch2        = (float*)ws;                    // 16 x 2.10 MB, overlays dead scratch1

    // 1) ba = X @ Wba^T  +  hs -> bf16
    ba_proj<<<S_LEN, 256, 0, stream>>>(hs, w_ba, ba, hs_bf);
    // 2) qkvz partials = Xbf @ Wqkvz^T (M=256,N=9216,K=2048), split-K=4, tile 256x64
    gemm_tile<<<dim3(QKVZ_N / 64, 1, 4), 256, 0, stream>>>(hs_bf, w_qkvz, scratch1, QKVZ_N, HID, HID / 4);
    // 3) partial-sum + causal depthwise conv + silu (qkv cols only)
    conv_red4<<<(S_LEN * CONVDIM) / 256, 256, 0, stream>>>(scratch1, conv_w, conv);
    // 4) fused scores -> @V -> gated RMSNorm -> bf16
    attn_fused<<<dim3(16, NVH), 256, 0, stream>>>(conv, ba, dt_bias, scratch1, norm_w, normed);
    // 5) out partials = normed @ Wout^T (M=256,N=2048,K=4096), split-K=16
    gemm_tile<<<dim3(HID / 64, 1, 16), 256, 0, stream>>>(normed, w_out, scratch2, HID, VALDIM, VALDIM / 16);
    // 6) reduce split-K -> d_out (fp32)
    reduce_sum<16><<<(S_LEN * HID) / 1024, 256, 0, stream>>>(scratch2, (float*)d_out, S_LEN * HID);
}

// Round 6
// 303.434 us; speedup vs baseline: 1.1075x; 1.1075x over previous
//
#include <hip/hip_runtime.h>
#include <hip/hip_bf16.h>

// Problem constants (Qwen3-Next linear attention defaults)
#define S_LEN   256
#define HID     2048
#define NVH     32
#define KEYDIM  512
#define VALDIM  4096
#define CONVDIM 5120
#define QKVZ_N  9216
#define EPS_F   1e-6f

typedef __attribute__((ext_vector_type(8))) short bf16x8;
typedef __attribute__((ext_vector_type(4))) float f32x4;

__device__ __forceinline__ unsigned short f2bf(float f) {
    union { float f; unsigned int i; } v; v.f = f;
    unsigned int x = v.i;
    return (unsigned short)((x + 0x7FFFu + ((x >> 16) & 1u)) >> 16); // RNE
}
__device__ __forceinline__ unsigned int pk2(float x, float y) {
    union { __hip_bfloat162 h; unsigned int u; } c;
    c.h = __float22bfloat162_rn(float2{x, y});
    return c.u;
}
__device__ __forceinline__ float4 asf4(uint4 u) {
    union { uint4 u; float4 f; } c; c.u = u; return c.f;
}
__device__ __forceinline__ uint4 cvt8_pack(float4 a, float4 b) {
    uint4 r;
    r.x = pk2(a.x, a.y); r.y = pk2(a.z, a.w);
    r.z = pk2(b.x, b.y); r.w = pk2(b.z, b.w);
    return r;
}
__device__ __forceinline__ float sigmoidf(float x) { return 1.f / (1.f + __expf(-x)); }

// ---------------------------------------------------------------------------
// Split-K MFMA GEMM, tile 128x128, BK=64, DOUBLE-BUFFERED LDS (1 barrier/iter).
// A bf16 [256,K]; B fp32 [N,K] (cvt->bf16 in staging). C fp32 partials.
// 4 waves 2x2. 128-col C strips per block (512B rows) -> no line false-sharing.
// mfma_f32_16x16x32_bf16: A-frag A[m=l16][k=quad*8+j]; C/D row=quad*4+r, col=l16.
// ---------------------------------------------------------------------------
__global__ __launch_bounds__(256, 2)
void gemm_tile(const unsigned short* __restrict__ A, const float* __restrict__ B,
               float* __restrict__ Cpart, int N, int K, int kc) {
    __shared__ __align__(16) unsigned short As[2][128][72];  // 144B row stride
    __shared__ __align__(16) unsigned short Bs[2][128][72];

    const int tid  = threadIdx.x;
    const int lane = tid & 63, wave = tid >> 6;
    const int wm = wave >> 1, wn = wave & 1;
    const int quad = lane >> 4, l16 = lane & 15;
    const int m0 = blockIdx.y * 128, n0 = blockIdx.x * 128;
    const int kbeg = blockIdx.z * kc;
    const int niter = kc >> 6;            // BK = 64

    const int arow = tid >> 3, acol = (tid & 7) << 3;  // A: 32 rows/pass x4, 16B/thread
    const int brow = tid >> 1, bcol = (tid & 1) << 5;  // B: 128 rows, 32 f32/thread

    f32x4 acc[4][4];
#pragma unroll
    for (int i = 0; i < 4; i++)
#pragma unroll
        for (int j = 0; j < 4; j++) acc[i][j] = (f32x4){0.f, 0.f, 0.f, 0.f};

    uint4 qa[4], qb[8];
    auto ld_tiles = [&](int kk) {
#pragma unroll
        for (int p = 0; p < 4; p++)
            qa[p] = *(const uint4*)(A + (size_t)(m0 + arow + 32 * p) * K + kk + acol);
        const float* b = B + (size_t)(n0 + brow) * K + kk + bcol;
#pragma unroll
        for (int i = 0; i < 8; i++) qb[i] = *(const uint4*)(b + 4 * i);
    };
    auto st_tiles = [&](int buf) {
#pragma unroll
        for (int p = 0; p < 4; p++)
            *(uint4*)(&As[buf][arow + 32 * p][acol]) = qa[p];
#pragma unroll
        for (int i = 0; i < 4; i++)
            *(uint4*)(&Bs[buf][brow][bcol + 8 * i]) = cvt8_pack(asf4(qb[2 * i]), asf4(qb[2 * i + 1]));
    };

    ld_tiles(kbeg);
    st_tiles(0);
    __syncthreads();

    for (int it = 0; it < niter; ++it) {
        const int cur = it & 1;
        if (it + 1 < niter) ld_tiles(kbeg + (it + 1) * 64);  // loads in flight over MFMAs

        bf16x8 af[2][4], bfr[2][4];
#pragma unroll
        for (int t = 0; t < 4; t++) {
#pragma unroll
            for (int ks = 0; ks < 2; ks++) {
                af[ks][t]  = *(const bf16x8*)(&As[cur][wm * 64 + t * 16 + l16][ks * 32 + quad * 8]);
                bfr[ks][t] = *(const bf16x8*)(&Bs[cur][wn * 64 + t * 16 + l16][ks * 32 + quad * 8]);
            }
        }
#pragma unroll
        for (int ks = 0; ks < 2; ks++)
#pragma unroll
            for (int i = 0; i < 4; i++)
#pragma unroll
                for (int j = 0; j < 4; j++)
                    acc[i][j] = __builtin_amdgcn_mfma_f32_16x16x32_bf16(af[ks][i], bfr[ks][j], acc[i][j], 0, 0, 0);

        if (it + 1 < niter) {
            st_tiles(cur ^ 1);   // write other buffer: no barrier needed before
            __syncthreads();     // single barrier per iter
        }
    }

    float* C = Cpart + (size_t)blockIdx.z * 256 * N;
#pragma unroll
    for (int i = 0; i < 4; i++)
#pragma unroll
        for (int j = 0; j < 4; j++)
#pragma unroll
            for (int r = 0; r < 4; r++) {
                int row = m0 + wm * 64 + i * 16 + quad * 4 + r;
                int col = n0 + wn * 64 + j * 16 + l16;
                C[(size_t)row * N + col] = acc[i][j][r];
            }
}

// sum P split-K partials, float4-vectorized
template<int P>
__global__ void reduce_sum(const float* __restrict__ part, float* __restrict__ out, int n) {
    int i = (blockIdx.x * 256 + threadIdx.x) * 4;
    if (i >= n) return;
    float4 s = *(const float4*)(part + i);
#pragma unroll
    for (int p = 1; p < P; p++) {
        float4 v = *(const float4*)(part + (size_t)p * n + i);
        s.x += v.x; s.y += v.y; s.z += v.z; s.w += v.w;
    }
    *(float4*)(out + i) = s;
}

// ba = hidden @ w_ba^T  [256,64]  +  hs -> bf16 copy (A operand for GEMM1).
__global__ __launch_bounds__(256)
void ba_proj(const float* __restrict__ hs,
             const float* __restrict__ w_ba,
             float* __restrict__ ba,
             unsigned short* __restrict__ hs_bf) {
    int s = blockIdx.x;
    int n = threadIdx.x & 63, seg = threadIdx.x >> 6;
    const float* x = hs + (size_t)s * HID + seg * 512;
    const float* w = w_ba + (size_t)n * HID + seg * 512;
    float acc = 0.f;
#pragma unroll 4
    for (int k = 0; k < 512; k += 4) {
        float4 xv = *(const float4*)(x + k);
        float4 wv = *(const float4*)(w + k);
        acc += xv.x * wv.x + xv.y * wv.y + xv.z * wv.z + xv.w * wv.w;
    }
    __shared__ float parts[4][64];
    parts[seg][n] = acc;
    int c = threadIdx.x * 8;
    float4 h0 = *(const float4*)(hs + (size_t)s * HID + c);
    float4 h1 = *(const float4*)(hs + (size_t)s * HID + c + 4);
    *(uint4*)(hs_bf + (size_t)s * HID + c) = cvt8_pack(h0, h1);
    __syncthreads();
    if (threadIdx.x < 64)
        ba[s * 64 + threadIdx.x] = parts[0][threadIdx.x] + parts[1][threadIdx.x]
                                 + parts[2][threadIdx.x] + parts[3][threadIdx.x];
}

// fused: sum 4 qkvz partials + causal depthwise conv (K=4) + silu, for qkv cols
__global__ void conv_red4(const float* __restrict__ part,
                          const float* __restrict__ conv_w,
                          float* __restrict__ out) {
    int idx = blockIdx.x * blockDim.x + threadIdx.x;
    int s = idx / CONVDIM, c = idx % CONVDIM;
    const size_t PSTR = (size_t)S_LEN * QKVZ_N;
    float acc = 0.f;
#pragma unroll
    for (int j = 0; j < 4; j++) {
        int t = s - 3 + j;
        if (t >= 0) {
            const float* p = part + (size_t)t * QKVZ_N + c;
            float q = p[0] + p[PSTR] + p[2 * PSTR] + p[3 * PSTR];
            acc += q * conv_w[c * 4 + j];
        }
    }
    out[idx] = acc * sigmoidf(acc); // silu
}

// fused flash-style: scores (QK^T * scale * beta_g, causal) -> @V -> gated
// RMSNorm -> bf16 normed.  Block = (s-tile of 16, v-head n).
__global__ __launch_bounds__(256)
void attn_fused(const float* __restrict__ conv, const float* __restrict__ ba,
                const float* __restrict__ dt_bias, const float* __restrict__ part,
                const float* __restrict__ norm_w,
                unsigned short* __restrict__ normed) {
    const int st = blockIdx.x, n = blockIdx.y, hk = n >> 3;
    const int s0 = st * 16;
    __shared__ float Qs[16][132], Ks[16][132], Vs[16][132], Ss[16][17];
    const int tid = threadIdx.x, sy = tid >> 4, dx = tid & 15;

    {   // stage Q tile
        const float* qp = conv + (size_t)(s0 + sy) * CONVDIM + hk * 128 + dx * 8;
        *(float4*)&Qs[sy][dx * 8]     = *(const float4*)qp;
        *(float4*)&Qs[sy][dx * 8 + 4] = *(const float4*)(qp + 4);
    }
    float acc[8] = {0.f, 0.f, 0.f, 0.f, 0.f, 0.f, 0.f, 0.f};
    const float dtb = dt_bias[n];

    for (int t0 = 0; t0 <= s0; t0 += 16) {
        const float* kp = conv + (size_t)(t0 + sy) * CONVDIM + KEYDIM + hk * 128 + dx * 8;
        const float* vp = conv + (size_t)(t0 + sy) * CONVDIM + 2 * KEYDIM + n * 128 + dx * 8;
        *(float4*)&Ks[sy][dx * 8]     = *(const float4*)kp;
        *(float4*)&Ks[sy][dx * 8 + 4] = *(const float4*)(kp + 4);
        *(float4*)&Vs[sy][dx * 8]     = *(const float4*)vp;
        *(float4*)&Vs[sy][dx * 8 + 4] = *(const float4*)(vp + 4);
        __syncthreads();
        float dot = 0.f;
#pragma unroll 8
        for (int d = 0; d < 128; d += 4) {
            float4 q = *(const float4*)&Qs[sy][d];
            float4 k = *(const float4*)&Ks[dx][d];
            dot += q.x * k.x + q.y * k.y + q.z * k.z + q.w * k.w;
        }
        int t = t0 + dx, s = s0 + sy;
        float bg = sigmoidf(ba[t * 64 + n] + dtb);
        Ss[sy][dx] = (t <= s) ? dot * 0.08838834764831845f * bg : 0.f;
        __syncthreads();
#pragma unroll
        for (int j = 0; j < 16; j++) {
            float sv = Ss[sy][j];
#pragma unroll
            for (int r = 0; r < 8; r++) acc[r] += sv * Vs[j][dx + 16 * r];
        }
        __syncthreads();
    }
    float ss = 0.f;
#pragma unroll
    for (int r = 0; r < 8; r++) ss += acc[r] * acc[r];
#pragma unroll
    for (int m = 1; m < 16; m <<= 1) ss += __shfl_xor(ss, m, 64);
    float inv = rsqrtf(ss * (1.f / 128.f) + EPS_F);
    const size_t PSTR = (size_t)S_LEN * QKVZ_N;
    const float* zb = part + (size_t)(s0 + sy) * QKVZ_N + CONVDIM + n * 128;
    unsigned short* op = normed + ((size_t)(s0 + sy) * NVH + n) * 128;
#pragma unroll
    for (int r = 0; r < 8; r++) {
        int d = dx + 16 * r;
        float z = zb[d] + zb[d + PSTR] + zb[d + 2 * PSTR] + zb[d + 3 * PSTR];
        float val = acc[r] * inv * norm_w[d] * (z * sigmoidf(z));
        op[d] = f2bf(val);
    }
}

extern "C" void kernel_launch(void* const* d_in, const int* in_sizes, int n_in,
                              void* d_out, int out_size, void* d_ws, size_t ws_size,
                              hipStream_t stream) {
    const float* hs      = (const float*)d_in[0];
    const float* w_qkvz  = (const float*)d_in[1];
    const float* w_ba    = (const float*)d_in[2];
    const float* w_out   = (const float*)d_in[3];
    const float* conv_w  = (const float*)d_in[4];
    const float* dt_bias = (const float*)d_in[5];
    const float* norm_w  = (const float*)d_in[7];

    // Workspace overlay (peak 46.2 MB; proven to fit in R5).
    char* ws = (char*)d_ws;
    float* scratch1        = (float*)ws;                       // 4 x 9.44 MB [gemm1 .. attn_fused]
    float* conv            = (float*)(ws + 37748736);          // 5.24 MB
    float* ba              = (float*)(ws + 42991616);          // 64 KB
    unsigned short* normed = (unsigned short*)(ws + 43057152); // 2.10 MB
    unsigned short* hs_bf  = (unsigned short*)(ws + 45154304); // 1.05 MB
    float* scratch2        = (float*)ws;                       // 16 x 2.10 MB, overlays dead scratch1

    // 1) ba = X @ Wba^T  +  hs -> bf16
    ba_proj<<<S_LEN, 256, 0, stream>>>(hs, w_ba, ba, hs_bf);
    // 2) qkvz partials = Xbf @ Wqkvz^T (M=256,N=9216,K=2048), split-K=4, tile 128x128
    gemm_tile<<<dim3(QKVZ_N / 128, 2, 4), 256, 0, stream>>>(hs_bf, w_qkvz, scratch1, QKVZ_N, HID, HID / 4);
    // 3) partial-sum + causal depthwise conv + silu (qkv cols only)
    conv_red4<<<(S_LEN * CONVDIM) / 256, 256, 0, stream>>>(scratch1, conv_w, conv);
    // 4) fused scores -> @V -> gated RMSNorm -> bf16
    attn_fused<<<dim3(16, NVH), 256, 0, stream>>>(conv, ba, dt_bias, scratch1, norm_w, normed);
    // 5) out partials = normed @ Wout^T (M=256,N=2048,K=4096), split-K=16
    gemm_tile<<<dim3(HID / 128, 2, 16), 256, 0, stream>>>(normed, w_out, scratch2, HID, VALDIM, VALDIM / 16);
    // 6) reduce split-K -> d_out (fp32)
    reduce_sum<16><<<(S_LEN * HID) / 1024, 256, 0, stream>>>(scratch2, (float*)d_out, S_LEN * HID);
}